// Round 16
// baseline (149.294 us; speedup 1.0000x reference)
//
#include <hip/hip_runtime.h>

#define TT 4096
#define BB 1024
#define LCH 5
#define CH 32
#define NC 128             // TT/CH
#define TB 4194304         // TT*BB
#define OFF_LOGP (TB)
#define OFF_ENT  (2*TB)
#define OFF_VAL  (3*TB)
#define OFF_HN   (4*TB)
#define OFF_CN   (4*TB + 16384)

#define NL2E  (-1.4426950408889634f)   // -log2(e)
#define N2L2E (-2.8853900817779268f)   // -2*log2(e)
#define LN4   (1.3862943611198906f)

typedef float    f32x2 __attribute__((ext_vector_type(2)));
typedef float    f32x4 __attribute__((ext_vector_type(4)));
typedef _Float16 f16x4 __attribute__((ext_vector_type(4)));
typedef _Float16 f16x8 __attribute__((ext_vector_type(8)));

__device__ __forceinline__ f32x4 splat4(float v){ return (f32x4){v,v,v,v}; }

__device__ __forceinline__ float fexp2(float x){
    return __builtin_amdgcn_exp2f(x);
}

// cubic-Taylor exp for |z| <~ 0.35 (rel err <= ~7e-5) — head softmax only
__device__ __forceinline__ float expp(float z){
    return fmaf(fmaf(fmaf(z, 0.16666667f, 0.5f), z, 1.f), z, 1.f);
}

// exact path (phase 3 only)
__device__ __forceinline__ float fsig(float x){
    return __builtin_amdgcn_rcpf(1.f + __expf(-x));
}
__device__ __forceinline__ float ftanh_(float x){
    return 1.f - 2.f*__builtin_amdgcn_rcpf(1.f + __expf(2.f*x));
}

// pack two f32x4 into one f16x8 (low 4 = a, high 4 = b)
__device__ __forceinline__ f16x8 pack8(f32x4 a, f32x4 b){
    f16x8 r;
    r[0]=(_Float16)a[0]; r[1]=(_Float16)a[1]; r[2]=(_Float16)a[2]; r[3]=(_Float16)a[3];
    r[4]=(_Float16)b[0]; r[5]=(_Float16)b[1]; r[6]=(_Float16)b[2]; r[7]=(_Float16)b[3];
    return r;
}

// Fused 16x16x32 MFMA: elems 0-3 = [wih | hid], elems 4-7 = [whh | h].
__device__ __forceinline__ f32x4 mfma32(f16x8 a, f16x8 b, f32x4 c){
    return __builtin_amdgcn_mfma_f32_16x16x32_f16(a, b, c, 0, 0, 0);
}

#define KPARAMS const float* __restrict__ x, const int* __restrict__ done, \
    const int* __restrict__ action, const float* __restrict__ h0, \
    const float* __restrict__ c0, const float* __restrict__ w1, \
    const float* __restrict__ b1, const float* __restrict__ w_ih, \
    const float* __restrict__ w_hh, const float* __restrict__ bsum, \
    const float* __restrict__ bsum_s, const float* __restrict__ wih_s, \
    const float* __restrict__ whh_s, const float* __restrict__ hw16, \
    const float* __restrict__ actor_w, const float* __restrict__ actor_b, \
    const float* __restrict__ critic_w, const float* __restrict__ critic_b, \
    float* __restrict__ out, float* __restrict__ carry, int* __restrict__ valid

#define KARGS x,done,action,h0,c0,w1,b1,w_ih,w_hh,bsum,bsum_s,wih_s,whh_s,hw16,actor_w,actor_b,critic_w,critic_b,out,carry,valid

// ---- per-wave constant fragments -----------------------------------------
// Wave handles 16 envs (env = lane&15 = lo). C/D mapping (verified):
// D[row=4*hi+r][col=lo]. B state fragment bb: elems 0-3 = hid[4hi+j]
// (locally computed), elems 4-7 = h[4hi+j] (own D-output rows -> transpose-
// free). Gate rows/biases PRE-SCALED: i,f,o by -log2e; g by -2log2e.
struct Frags {
    f16x8 wA[4];      // gate tile mt: [wih row | whh row]
    f16x8 hwA;        // head: [0 | hw16 row]
    f32x4 biasC[4], biasH;
    f32x2 w1r[4];
    f32x4 b1r;
};

__device__ __forceinline__ void load_frags(Frags& F, int lo, int hi,
    const float* w1, const float* b1, const float* wih_s, const float* whh_s,
    const float* bsum_s, const float* hw16, const float* actor_b,
    const float* critic_b)
{
#pragma unroll
    for (int mt = 0; mt < 4; mt++) {
        f32x4 wi = *(const f32x4*)(wih_s + (16*mt+lo)*16 + 4*hi);
        f32x4 wh = *(const f32x4*)(whh_s + (16*mt+lo)*16 + 4*hi);
        F.wA[mt]    = pack8(wi, wh);
        F.biasC[mt] = *(const f32x4*)(bsum_s + 16*mt + 4*hi);
    }
    F.hwA = pack8(splat4(0.f), *(const f32x4*)(hw16 + lo*16 + 4*hi));
    if (hi == 0)       F.biasH = *(const f32x4*)(actor_b);
    else if (hi == 1)  F.biasH = (f32x4){critic_b[0], 0.f, 0.f, 0.f};
    else               F.biasH = splat4(0.f);
#pragma unroll
    for (int r = 0; r < 4; r++) {
        F.w1r[r] = *(const f32x2*)(w1 + (4*hi+r)*2);
        F.b1r[r] = b1[4*hi+r];
    }
}

// MLP encoder: hid rows 4hi..4hi+3 for this lane.
__device__ __forceinline__ f32x4 enc_hid(const Frags& F, f32x2 xv)
{
    f32x4 hid;
#pragma unroll
    for (int r = 0; r < 4; r++)
        hid[r] = fmaxf(fmaf(F.w1r[r][0], xv[0], fmaf(F.w1r[r][1], xv[1], F.b1r[r])), 0.f);
    return hid;
}

// Activations + cell update. g0,g1,g3 = -log2e*(i,f,o); g2 = -2log2e*g.
// Gates: QUAD-shared rcp (preacts weight-bounded -> product < 2^80, safe).
// tanh(c): PAIRED rcp (c accumulates over segments; quad could overflow).
__device__ __forceinline__ f32x4 gates_act(f32x4 g0, f32x4 g1, f32x4 g2, f32x4 g3,
                                           f32x4& cc)
{
    f32x4 o4, cv4;
#pragma unroll
    for (int r = 0; r < 4; r++) {
        float A0 = 1.f + fexp2(g0[r]);           // i
        float A1 = 1.f + fexp2(g1[r]);           // f
        float A2 = 1.f + fexp2(g2[r]);           // g (tanh via 2*sig-1)
        float A3 = 1.f + fexp2(g3[r]);           // o
        float P01 = A0*A1, P23 = A2*A3;
        float R = __builtin_amdgcn_rcpf(P01*P23);
        float P23R = P23*R;                      // = 1/P01
        float P01R = P01*R;                      // = 1/P23
        float si = A1*P23R;                      // 1/A0
        float sf = A0*P23R;                      // 1/A1
        float tg = fmaf(2.f, A3*P01R, -1.f);     // 2/A2 - 1
        o4[r]    = A2*P01R;                      // 1/A3
        cv4[r]   = fmaf(sf, cc[r], si*tg);
    }
    cc = cv4;
    float B0 = 1.f + fexp2(N2L2E*cv4[0]);
    float B1 = 1.f + fexp2(N2L2E*cv4[1]);
    float B2 = 1.f + fexp2(N2L2E*cv4[2]);
    float B3 = 1.f + fexp2(N2L2E*cv4[3]);
    float Ra = __builtin_amdgcn_rcpf(B0*B1);
    float Rb = __builtin_amdgcn_rcpf(B2*B3);
    f32x4 hn;
    hn[0] = o4[0]*fmaf(2.f, B1*Ra, -1.f);
    hn[1] = o4[1]*fmaf(2.f, B0*Ra, -1.f);
    hn[2] = o4[2]*fmaf(2.f, B3*Rb, -1.f);
    hn[3] = o4[3]*fmaf(2.f, B2*Rb, -1.f);
    return hn;
}

// Softmax + predicated stores — trans-free except one rcp.
// |logits| <~0.3 by construction (actor_w 0.01-scale, |h|<=1):
// cubic-Taylor exp, u-series log around s=4.
__device__ __forceinline__ void soft_store(f32x4 dh, int a, int idx,
    bool do_store, int hi, float* __restrict__ out)
{
    if (do_store) {
        if (hi == 0) {
            float e0 = expp(dh[0]), e1 = expp(dh[1]);
            float e2 = expp(dh[2]), e3 = expp(dh[3]);
            float s  = e0+e1+e2+e3;
            float inv = __builtin_amdgcn_rcpf(s);
            float u  = fmaf(0.25f, s, -1.f);
            float ls = fmaf(fmaf(fmaf(u, 0.33333333f, -0.5f), u, 1.f), u, LN4);
            float t  = e0*dh[0] + e1*dh[1] + e2*dh[2] + e3*dh[3];
            float ent = ls - t*inv;
            float lsel = (a==0) ? dh[0] : (a==1) ? dh[1] : (a==2) ? dh[2] : dh[3];
            out[idx]            = (float)a;
            out[OFF_LOGP + idx] = lsel - ls;
            out[OFF_ENT  + idx] = ent;
        } else if (hi == 1) {
            out[OFF_VAL + idx] = dh[0];
        }
    }
}

// Phase 1: every (env, chunk) from zero state with done-masking.
__global__ __launch_bounds__(256) __attribute__((amdgpu_waves_per_eu(4, 8)))
void k_phase1(KPARAMS)
{
    const int tid  = blockIdx.x*256 + threadIdx.x;
    const int lane = tid & 63;
    const int lo = lane & 15, hi = lane >> 4;
    const int w    = tid >> 6;
    const int ch   = w >> 6;                 // BB/16 = 64 waves per chunk
    const int base = (w & 63) << 4;
    const int b    = base + lo;
    const int t0   = ch << LCH;

    Frags F;
    load_frags(F, lo, hi, w1, b1, wih_s, whh_s, bsum_s, hw16, actor_b, critic_b);

    f32x4 cc = splat4(0.f);
    int hr = 0;

    const int i0 = t0*BB + b;
    int   d_cur = done[i0];
    f32x2 x_cur = *(const f32x2*)(x + 2*(size_t)i0);
    int   a_cur = action[i0];

    f16x8 bb = pack8(enc_hid(F, x_cur), splat4(0.f));   // hid | h=0

#pragma unroll 2
    for (int s = 0; s < CH; s++) {
        const int idx = (t0 + s)*BB + b;
        int d_nxt = 0, a_nxt = 0;
        f32x2 x_nxt = (f32x2){0.f, 0.f};
        if (s + 1 < CH) {
            d_nxt = done[idx + BB];
            x_nxt = *(const f32x2*)(x + 2*(size_t)(idx + BB));
            a_nxt = action[idx + BB];
        }
        hr |= d_cur;
        if (d_cur) {
            bb[4]=(_Float16)0.f; bb[5]=(_Float16)0.f;
            bb[6]=(_Float16)0.f; bb[7]=(_Float16)0.f;
            cc = splat4(0.f);
        }
        f32x4 g0 = mfma32(F.wA[0], bb, F.biasC[0]);
        f32x4 g1 = mfma32(F.wA[1], bb, F.biasC[1]);
        f32x4 g2 = mfma32(F.wA[2], bb, F.biasC[2]);
        f32x4 g3 = mfma32(F.wA[3], bb, F.biasC[3]);
        f32x4 hn = gates_act(g0, g1, g2, g3, cc);
        f16x8 bn = pack8(enc_hid(F, x_nxt), hn);        // next step's B
        f32x4 dh = mfma32(F.hwA, bn, F.biasH);          // head uses h part only
        soft_store(dh, a_cur, idx, true, hi, out);
        bb = bn; d_cur = d_nxt; a_cur = a_nxt;
    }
    if (hr) {
#pragma unroll
        for (int r = 0; r < 4; r++) {
            carry[(ch*32 + 4*hi + r)*BB + b]      = (float)bb[4+r];
            carry[(ch*32 + 16 + 4*hi + r)*BB + b] = cc[r];
        }
    }
    if (hi == 0) valid[ch*BB + b] = hr;
}

// Phase 2: redo the pre-first-reset prefix of each chunk with the true carry.
__global__ __launch_bounds__(256) __attribute__((amdgpu_waves_per_eu(4, 8)))
void k_phase2(KPARAMS)
{
    const int tid  = blockIdx.x*256 + threadIdx.x;
    const int lane = tid & 63;
    const int lo = lane & 15, hi = lane >> 4;
    const int w    = tid >> 6;
    const int ch   = w >> 6;
    const int base = (w & 63) << 4;
    const int b    = base + lo;
    const int t0   = ch << LCH;

    Frags F;
    load_frags(F, lo, hi, w1, b1, wih_s, whh_s, bsum_s, hw16, actor_b, critic_b);

    f32x4 hf, cc;
    bool active;
    if (ch == 0) {
        hf = *(const f32x4*)(h0 + b*16 + 4*hi);
        cc = *(const f32x4*)(c0 + b*16 + 4*hi);
        active = true;
    } else {
        active = (valid[(ch-1)*BB + b] != 0);
#pragma unroll
        for (int r = 0; r < 4; r++) {
            hf[r] = carry[((ch-1)*32 + 4*hi + r)*BB + b];
            cc[r] = carry[((ch-1)*32 + 16 + 4*hi + r)*BB + b];
        }
    }

    const int i0 = t0*BB + b;
    f32x2 x_cur = *(const f32x2*)(x + 2*(size_t)i0);
    f16x8 bb = pack8(enc_hid(F, x_cur), hf);

    for (int s = 0; s < CH; s++) {
        if (!__ballot(active)) break;
        const int idx = (t0 + s)*BB + b;
        const int d = done[idx];
        if (d) active = false;                 // phase-1 value exact from here
        f32x2 x_nxt = (f32x2){0.f, 0.f};
        if (s + 1 < CH)
            x_nxt = *(const f32x2*)(x + 2*(size_t)(idx + BB));
        const int a = action[idx];
        f32x4 g0 = mfma32(F.wA[0], bb, F.biasC[0]);
        f32x4 g1 = mfma32(F.wA[1], bb, F.biasC[1]);
        f32x4 g2 = mfma32(F.wA[2], bb, F.biasC[2]);
        f32x4 g3 = mfma32(F.wA[3], bb, F.biasC[3]);
        f32x4 hn = gates_act(g0, g1, g2, g3, cc);
        f16x8 bn = pack8(enc_hid(F, x_nxt), hn);
        f32x4 dh = mfma32(F.hwA, bn, F.biasH);
        soft_store(dh, a, idx, active, hi, out);
        bb = bn;
    }

    if (ch == NC-1) {
        if (active) {                          // no reset in entire chunk
#pragma unroll
            for (int r = 0; r < 4; r++) {
                out[OFF_HN + b*16 + 4*hi + r] = (float)bb[4+r];
                out[OFF_CN + b*16 + 4*hi + r] = cc[r];
            }
        } else if (valid[(NC-1)*BB + b]) {
#pragma unroll
            for (int r = 0; r < 4; r++) {
                out[OFF_HN + b*16 + 4*hi + r] = carry[((NC-1)*32 + 4*hi + r)*BB + b];
                out[OFF_CN + b*16 + 4*hi + r] = carry[((NC-1)*32 + 16 + 4*hi + r)*BB + b];
            }
        } // else: phase 3 writes
    }
}

// ---- exact scalar f32 fallback cell (phase 3 only; ~never executes) ------
__device__ void cell_scalar(const float* x, const int* action,
    const float* w1, const float* b1, const float* w_ih, const float* w_hh,
    const float* bsum, const float* actor_w, const float* actor_b,
    const float* critic_w, const float* critic_b, float* out,
    int t, int b, float h[16], float c[16])
{
    const int idx = t*BB + b;
    float x0 = x[2*(size_t)idx], x1 = x[2*(size_t)idx+1];
    float hid[16];
#pragma unroll
    for (int k = 0; k < 16; k++)
        hid[k] = fmaxf(fmaf(w1[2*k], x0, fmaf(w1[2*k+1], x1, b1[k])), 0.f);
    float nh[16], nc[16];
#pragma unroll
    for (int k = 0; k < 16; k++) {
        float ai = bsum[k], af = bsum[16+k], ag = bsum[32+k], ao = bsum[48+k];
#pragma unroll
        for (int j = 0; j < 16; j++) {
            ai = fmaf(w_ih[k*16+j],      hid[j], ai);
            af = fmaf(w_ih[(16+k)*16+j], hid[j], af);
            ag = fmaf(w_ih[(32+k)*16+j], hid[j], ag);
            ao = fmaf(w_ih[(48+k)*16+j], hid[j], ao);
        }
#pragma unroll
        for (int j = 0; j < 16; j++) {
            ai = fmaf(w_hh[k*16+j],      h[j], ai);
            af = fmaf(w_hh[(16+k)*16+j], h[j], af);
            ag = fmaf(w_hh[(32+k)*16+j], h[j], ag);
            ao = fmaf(w_hh[(48+k)*16+j], h[j], ao);
        }
        float si = fsig(ai), sf = fsig(af), sg = ftanh_(ag), so = fsig(ao);
        float cv = fmaf(sf, c[k], si*sg);
        nc[k] = cv; nh[k] = so*ftanh_(cv);
    }
#pragma unroll
    for (int k = 0; k < 16; k++) { h[k] = nh[k]; c[k] = nc[k]; }
    float l0=actor_b[0], l1=actor_b[1], l2=actor_b[2], l3=actor_b[3], v=critic_b[0];
#pragma unroll
    for (int j = 0; j < 16; j++) {
        l0 = fmaf(actor_w[j],    h[j], l0);
        l1 = fmaf(actor_w[16+j], h[j], l1);
        l2 = fmaf(actor_w[32+j], h[j], l2);
        l3 = fmaf(actor_w[48+j], h[j], l3);
        v  = fmaf(critic_w[j],   h[j], v);
    }
    float mx = fmaxf(fmaxf(l0,l1), fmaxf(l2,l3));
    float e0=__expf(l0-mx), e1=__expf(l1-mx), e2=__expf(l2-mx), e3=__expf(l3-mx);
    float s = e0+e1+e2+e3, ls = __logf(s), inv = __builtin_amdgcn_rcpf(s);
    float lp0=l0-mx-ls, lp1=l1-mx-ls, lp2=l2-mx-ls, lp3=l3-mx-ls;
    int a = action[idx];
    float lp = (a==0)?lp0:(a==1)?lp1:(a==2)?lp2:lp3;
    out[idx]            = (float)a;
    out[OFF_LOGP + idx] = lp;
    out[OFF_ENT  + idx] = -(e0*lp0+e1*lp1+e2*lp2+e3*lp3)*inv;
    out[OFF_VAL  + idx] = v;
}

// Phase 3: sequential per-env fixup for chunks with no reset (P ~ 2^-32 each).
__global__ void k_phase3(KPARAMS)
{
    int b = blockIdx.x*blockDim.x + threadIdx.x;
    if (b >= BB) return;
    bool anybad = false;
    for (int ch = 0; ch < NC; ch++) anybad |= (valid[ch*BB + b] == 0);
    if (!anybad) return;

    int fixed_until = 0;
    for (int ch = 0; ch < NC; ch++) {
        if (valid[ch*BB + b]) continue;
        int t0 = ch << LCH;
        if (t0 < fixed_until) continue;
        float h[16], c[16];
        if (ch == 0) {
#pragma unroll
            for (int k = 0; k < 16; k++) { h[k] = h0[b*16+k]; c[k] = c0[b*16+k]; }
        } else {
#pragma unroll
            for (int k = 0; k < 16; k++) {
                h[k] = carry[((ch-1)*32 + k)*BB + b];
                c[k] = carry[((ch-1)*32 + 16 + k)*BB + b];
            }
        }
        int t;
        for (t = t0; t < TT; t++) {
            if (done[t*BB + b]) break;
            cell_scalar(x, action, w1, b1, w_ih, w_hh, bsum,
                        actor_w, actor_b, critic_w, critic_b, out, t, b, h, c);
            if (((t+1) & (CH-1)) == 0) {
                int cc2 = t >> LCH;
#pragma unroll
                for (int k = 0; k < 16; k++) {
                    carry[(cc2*32 + k)*BB + b]      = h[k];
                    carry[(cc2*32 + 16 + k)*BB + b] = c[k];
                }
                valid[cc2*BB + b] = 1;
            }
        }
        if (t == TT) {
#pragma unroll
            for (int k = 0; k < 16; k++) {
                out[OFF_HN + b*16 + k] = h[k];
                out[OFF_CN + b*16 + k] = c[k];
            }
        }
        fixed_until = t;
    }
    if (valid[(NC-1)*BB + b]) {
#pragma unroll
        for (int k = 0; k < 16; k++) {
            out[OFF_HN + b*16 + k] = carry[((NC-1)*32 + k)*BB + b];
            out[OFF_CN + b*16 + k] = carry[((NC-1)*32 + 16 + k)*BB + b];
        }
    }
}

// Prep: bsum exact (phase3); bsum_s/wih_s/whh_s pre-scaled for exp2 gates
// (i,f,o rows: -log2e; g rows 32..47: -2log2e); hw16 head matrix.
__global__ void k_prep(const float* __restrict__ b_ih, const float* __restrict__ b_hh,
                       const float* __restrict__ w_ih, const float* __restrict__ w_hh,
                       const float* __restrict__ actor_w, const float* __restrict__ critic_w,
                       float* __restrict__ bsum, float* __restrict__ bsum_s,
                       float* __restrict__ hw16, float* __restrict__ wih_s,
                       float* __restrict__ whh_s)
{
    int i = threadIdx.x;
    if (i < 64) {
        float s = b_ih[i] + b_hh[i];
        bsum[i] = s;
        bool isg = (i >= 32) && (i < 48);
        bsum_s[i] = s * (isg ? N2L2E : NL2E);
    }
    {
        int row = i >> 4, k = i & 15;
        float v = 0.f;
        if (row < 4)        v = actor_w[row*16 + k];
        else if (row == 4)  v = critic_w[k];
        hw16[i] = v;
    }
    for (int j = i; j < 1024; j += 256) {
        int row = j >> 4;
        float sc = ((row >= 32) && (row < 48)) ? N2L2E : NL2E;
        wih_s[j] = sc * w_ih[j];
        whh_s[j] = sc * w_hh[j];
    }
}

extern "C" void kernel_launch(void* const* d_in, const int* in_sizes, int n_in,
                              void* d_out, int out_size, void* d_ws, size_t ws_size,
                              hipStream_t stream)
{
    const float* x        = (const float*)d_in[0];
    const int*   done     = (const int*)  d_in[1];
    const int*   action   = (const int*)  d_in[2];
    const float* h0       = (const float*)d_in[3];
    const float* c0       = (const float*)d_in[4];
    const float* w1       = (const float*)d_in[5];
    const float* b1       = (const float*)d_in[6];
    const float* w_ih     = (const float*)d_in[7];
    const float* w_hh     = (const float*)d_in[8];
    const float* b_ih     = (const float*)d_in[9];
    const float* b_hh     = (const float*)d_in[10];
    const float* actor_w  = (const float*)d_in[11];
    const float* actor_b  = (const float*)d_in[12];
    const float* critic_w = (const float*)d_in[13];
    const float* critic_b = (const float*)d_in[14];
    float* out = (float*)d_out;

    // ws: bsum@0 | bsum_s@256 | hw16@512 | wih_s@1536 | whh_s@5632 | carry@16384 | valid
    float* bsum   = (float*)d_ws;
    float* bsum_s = (float*)((char*)d_ws + 256);
    float* hw16   = (float*)((char*)d_ws + 512);
    float* wih_s  = (float*)((char*)d_ws + 1536);
    float* whh_s  = (float*)((char*)d_ws + 5632);
    float* carry  = (float*)((char*)d_ws + 16384);
    int*   valid  = (int*)((char*)d_ws + 16384 + (size_t)NC*32*BB*4);

    hipLaunchKernelGGL(k_prep, dim3(1), dim3(256), 0, stream,
                       b_ih, b_hh, w_ih, w_hh, actor_w, critic_w,
                       bsum, bsum_s, hw16, wih_s, whh_s);

    const int nthreads = NC*(BB/16)*64;            // one wave per 16 envs
    hipLaunchKernelGGL(k_phase1, dim3(nthreads/256), dim3(256), 0, stream, KARGS);
    hipLaunchKernelGGL(k_phase2, dim3(nthreads/256), dim3(256), 0, stream, KARGS);
    hipLaunchKernelGGL(k_phase3, dim3(BB/256), dim3(256), 0, stream, KARGS);
}

// Round 17
// 145.720 us; speedup vs baseline: 1.0245x; 1.0245x over previous
//
#include <hip/hip_runtime.h>

#define TT 4096
#define BB 1024
#define LCH 5
#define CH 32
#define NC 128             // TT/CH
#define TB 4194304         // TT*BB
#define OFF_LOGP (TB)
#define OFF_ENT  (2*TB)
#define OFF_VAL  (3*TB)
#define OFF_HN   (4*TB)
#define OFF_CN   (4*TB + 16384)

#define NL2E  (-1.4426950408889634f)   // -log2(e)
#define N2L2E (-2.8853900817779268f)   // -2*log2(e)

typedef float    f32x2 __attribute__((ext_vector_type(2)));
typedef float    f32x4 __attribute__((ext_vector_type(4)));
typedef _Float16 f16x4 __attribute__((ext_vector_type(4)));
typedef _Float16 f16x8 __attribute__((ext_vector_type(8)));

__device__ __forceinline__ f32x4 splat4(float v){ return (f32x4){v,v,v,v}; }

__device__ __forceinline__ float fexp2(float x){
    return __builtin_amdgcn_exp2f(x);
}

// exact path (phase 3 only)
__device__ __forceinline__ float fsig(float x){
    return __builtin_amdgcn_rcpf(1.f + __expf(-x));
}
__device__ __forceinline__ float ftanh_(float x){
    return 1.f - 2.f*__builtin_amdgcn_rcpf(1.f + __expf(2.f*x));
}

// pack two f32x4 into one f16x8 (low 4 = a, high 4 = b)
__device__ __forceinline__ f16x8 pack8(f32x4 a, f32x4 b){
    f16x8 r;
    r[0]=(_Float16)a[0]; r[1]=(_Float16)a[1]; r[2]=(_Float16)a[2]; r[3]=(_Float16)a[3];
    r[4]=(_Float16)b[0]; r[5]=(_Float16)b[1]; r[6]=(_Float16)b[2]; r[7]=(_Float16)b[3];
    return r;
}

// Fused 16x16x32 MFMA: elems 0-3 = [wih | hid], elems 4-7 = [whh | h].
__device__ __forceinline__ f32x4 mfma32(f16x8 a, f16x8 b, f32x4 c){
    return __builtin_amdgcn_mfma_f32_16x16x32_f16(a, b, c, 0, 0, 0);
}

#define KPARAMS const float* __restrict__ x, const int* __restrict__ done, \
    const int* __restrict__ action, const float* __restrict__ h0, \
    const float* __restrict__ c0, const float* __restrict__ w1, \
    const float* __restrict__ b1, const float* __restrict__ w_ih, \
    const float* __restrict__ w_hh, const float* __restrict__ bsum, \
    const float* __restrict__ bsum_s, const float* __restrict__ wih_s, \
    const float* __restrict__ whh_s, const float* __restrict__ hw16, \
    const float* __restrict__ actor_w, const float* __restrict__ actor_b, \
    const float* __restrict__ critic_w, const float* __restrict__ critic_b, \
    float* __restrict__ out, float* __restrict__ carry, int* __restrict__ valid

#define KARGS x,done,action,h0,c0,w1,b1,w_ih,w_hh,bsum,bsum_s,wih_s,whh_s,hw16,actor_w,actor_b,critic_w,critic_b,out,carry,valid

// ---- per-wave constant fragments -----------------------------------------
// Wave handles 16 envs (env = lane&15 = lo). C/D mapping (verified):
// D[row=4*hi+r][col=lo]. B state fragment bb: elems 0-3 = hid[4hi+j]
// (locally computed), elems 4-7 = h[4hi+j] (own D-output rows -> transpose-
// free). Gate rows/biases PRE-SCALED: i,f,o by -log2e; g by -2log2e.
struct Frags {
    f16x8 wA[4];      // gate tile mt: [wih row | whh row]
    f16x8 hwA;        // head: [0 | hw16 row]
    f32x4 biasC[4], biasH;
    f32x2 w1r[4];
    f32x4 b1r;
};

__device__ __forceinline__ void load_frags(Frags& F, int lo, int hi,
    const float* w1, const float* b1, const float* wih_s, const float* whh_s,
    const float* bsum_s, const float* hw16, const float* actor_b,
    const float* critic_b)
{
#pragma unroll
    for (int mt = 0; mt < 4; mt++) {
        f32x4 wi = *(const f32x4*)(wih_s + (16*mt+lo)*16 + 4*hi);
        f32x4 wh = *(const f32x4*)(whh_s + (16*mt+lo)*16 + 4*hi);
        F.wA[mt]    = pack8(wi, wh);
        F.biasC[mt] = *(const f32x4*)(bsum_s + 16*mt + 4*hi);
    }
    F.hwA = pack8(splat4(0.f), *(const f32x4*)(hw16 + lo*16 + 4*hi));
    if (hi == 0)       F.biasH = *(const f32x4*)(actor_b);
    else if (hi == 1)  F.biasH = (f32x4){critic_b[0], 0.f, 0.f, 0.f};
    else               F.biasH = splat4(0.f);
#pragma unroll
    for (int r = 0; r < 4; r++) {
        F.w1r[r] = *(const f32x2*)(w1 + (4*hi+r)*2);
        F.b1r[r] = b1[4*hi+r];
    }
}

// MLP encoder: hid rows 4hi..4hi+3 for this lane.
__device__ __forceinline__ f32x4 enc_hid(const Frags& F, f32x2 xv)
{
    f32x4 hid;
#pragma unroll
    for (int r = 0; r < 4; r++)
        hid[r] = fmaxf(fmaf(F.w1r[r][0], xv[0], fmaf(F.w1r[r][1], xv[1], F.b1r[r])), 0.f);
    return hid;
}

// Activations + cell update. g0,g1,g3 = -log2e*(i,f,o); g2 = -2log2e*g.
// Paired rcp. Returns hn (f32), updates cc.
__device__ __forceinline__ f32x4 gates_act(f32x4 g0, f32x4 g1, f32x4 g2, f32x4 g3,
                                           f32x4& cc)
{
    f32x4 o4, cv4;
#pragma unroll
    for (int r = 0; r < 4; r++) {
        float A0 = 1.f + fexp2(g0[r]);           // i
        float A1 = 1.f + fexp2(g1[r]);           // f
        float A2 = 1.f + fexp2(g2[r]);           // g (tanh via 2*sig-1)
        float A3 = 1.f + fexp2(g3[r]);           // o
        float R01 = __builtin_amdgcn_rcpf(A0*A1);
        float R23 = __builtin_amdgcn_rcpf(A2*A3);
        float si = A1*R01;
        float sf = A0*R01;
        float tg = fmaf(2.f, A3*R23, -1.f);      // tanh(g)
        o4[r]    = A2*R23;                       // sigma(o)
        cv4[r]   = fmaf(sf, cc[r], si*tg);
    }
    cc = cv4;
    float B0 = 1.f + fexp2(N2L2E*cv4[0]);
    float B1 = 1.f + fexp2(N2L2E*cv4[1]);
    float B2 = 1.f + fexp2(N2L2E*cv4[2]);
    float B3 = 1.f + fexp2(N2L2E*cv4[3]);
    float Ra = __builtin_amdgcn_rcpf(B0*B1);
    float Rb = __builtin_amdgcn_rcpf(B2*B3);
    f32x4 hn;
    hn[0] = o4[0]*fmaf(2.f, B1*Ra, -1.f);
    hn[1] = o4[1]*fmaf(2.f, B0*Ra, -1.f);
    hn[2] = o4[2]*fmaf(2.f, B3*Rb, -1.f);
    hn[3] = o4[3]*fmaf(2.f, B2*Rb, -1.f);
    return hn;
}

// Softmax + predicated stores. dh from head MFMA.
__device__ __forceinline__ void soft_store(f32x4 dh, int a, int idx,
    bool do_store, int hi, float* __restrict__ out)
{
    if (do_store) {
        if (hi == 0) {
            float e0 = __expf(dh[0]), e1 = __expf(dh[1]);
            float e2 = __expf(dh[2]), e3 = __expf(dh[3]);
            float s  = e0+e1+e2+e3;
            float ls = __logf(s);
            float t  = e0*dh[0] + e1*dh[1] + e2*dh[2] + e3*dh[3];
            float ent = ls - t*__builtin_amdgcn_rcpf(s);
            float lsel = (a==0) ? dh[0] : (a==1) ? dh[1] : (a==2) ? dh[2] : dh[3];
            out[idx]            = (float)a;
            out[OFF_LOGP + idx] = lsel - ls;
            out[OFF_ENT  + idx] = ent;
        } else if (hi == 1) {
            out[OFF_VAL + idx] = dh[0];
        }
    }
}

// Phase 1: every (env, chunk) from zero state with done-masking.
// 64-thread blocks (1 wave) for fine-grained residency.
__global__ __launch_bounds__(64) __attribute__((amdgpu_waves_per_eu(4, 8)))
void k_phase1(KPARAMS)
{
    const int tid  = blockIdx.x*64 + threadIdx.x;
    const int lane = tid & 63;
    const int lo = lane & 15, hi = lane >> 4;
    const int w    = tid >> 6;
    const int ch   = w >> 6;                 // BB/16 = 64 waves per chunk
    const int base = (w & 63) << 4;
    const int b    = base + lo;
    const int t0   = ch << LCH;

    Frags F;
    load_frags(F, lo, hi, w1, b1, wih_s, whh_s, bsum_s, hw16, actor_b, critic_b);

    f32x4 cc = splat4(0.f);
    int hr = 0;

    const int i0 = t0*BB + b;
    int   d_cur = done[i0];
    f32x2 x_cur = *(const f32x2*)(x + 2*(size_t)i0);
    int   a_cur = action[i0];

    f16x8 bb = pack8(enc_hid(F, x_cur), splat4(0.f));   // hid | h=0

#pragma unroll 2
    for (int s = 0; s < CH; s++) {
        const int idx = (t0 + s)*BB + b;
        int d_nxt = 0, a_nxt = 0;
        f32x2 x_nxt = (f32x2){0.f, 0.f};
        if (s + 1 < CH) {
            d_nxt = done[idx + BB];
            x_nxt = *(const f32x2*)(x + 2*(size_t)(idx + BB));
            a_nxt = action[idx + BB];
        }
        hr |= d_cur;
        if (d_cur) {
            bb[4]=(_Float16)0.f; bb[5]=(_Float16)0.f;
            bb[6]=(_Float16)0.f; bb[7]=(_Float16)0.f;
            cc = splat4(0.f);
        }
        f32x4 g0 = mfma32(F.wA[0], bb, F.biasC[0]);
        f32x4 g1 = mfma32(F.wA[1], bb, F.biasC[1]);
        f32x4 g2 = mfma32(F.wA[2], bb, F.biasC[2]);
        f32x4 g3 = mfma32(F.wA[3], bb, F.biasC[3]);
        f32x4 hn = gates_act(g0, g1, g2, g3, cc);
        f16x8 bn = pack8(enc_hid(F, x_nxt), hn);        // next step's B
        f32x4 dh = mfma32(F.hwA, bn, F.biasH);          // head uses h part only
        soft_store(dh, a_cur, idx, true, hi, out);
        bb = bn; d_cur = d_nxt; a_cur = a_nxt;
    }
    if (hr) {
#pragma unroll
        for (int r = 0; r < 4; r++) {
            carry[(ch*32 + 4*hi + r)*BB + b]      = (float)bb[4+r];
            carry[(ch*32 + 16 + 4*hi + r)*BB + b] = cc[r];
        }
    }
    if (hi == 0) valid[ch*BB + b] = hr;
}

// Phase 2: redo the pre-first-reset prefix of each chunk with the true carry.
__global__ __launch_bounds__(64) __attribute__((amdgpu_waves_per_eu(4, 8)))
void k_phase2(KPARAMS)
{
    const int tid  = blockIdx.x*64 + threadIdx.x;
    const int lane = tid & 63;
    const int lo = lane & 15, hi = lane >> 4;
    const int w    = tid >> 6;
    const int ch   = w >> 6;
    const int base = (w & 63) << 4;
    const int b    = base + lo;
    const int t0   = ch << LCH;

    Frags F;
    load_frags(F, lo, hi, w1, b1, wih_s, whh_s, bsum_s, hw16, actor_b, critic_b);

    f32x4 hf, cc;
    bool active;
    if (ch == 0) {
        hf = *(const f32x4*)(h0 + b*16 + 4*hi);
        cc = *(const f32x4*)(c0 + b*16 + 4*hi);
        active = true;
    } else {
        active = (valid[(ch-1)*BB + b] != 0);
#pragma unroll
        for (int r = 0; r < 4; r++) {
            hf[r] = carry[((ch-1)*32 + 4*hi + r)*BB + b];
            cc[r] = carry[((ch-1)*32 + 16 + 4*hi + r)*BB + b];
        }
    }

    const int i0 = t0*BB + b;
    f32x2 x_cur = *(const f32x2*)(x + 2*(size_t)i0);
    f16x8 bb = pack8(enc_hid(F, x_cur), hf);

    for (int s = 0; s < CH; s++) {
        if (!__ballot(active)) break;
        const int idx = (t0 + s)*BB + b;
        const int d = done[idx];
        if (d) active = false;                 // phase-1 value exact from here
        f32x2 x_nxt = (f32x2){0.f, 0.f};
        if (s + 1 < CH)
            x_nxt = *(const f32x2*)(x + 2*(size_t)(idx + BB));
        const int a = action[idx];
        f32x4 g0 = mfma32(F.wA[0], bb, F.biasC[0]);
        f32x4 g1 = mfma32(F.wA[1], bb, F.biasC[1]);
        f32x4 g2 = mfma32(F.wA[2], bb, F.biasC[2]);
        f32x4 g3 = mfma32(F.wA[3], bb, F.biasC[3]);
        f32x4 hn = gates_act(g0, g1, g2, g3, cc);
        f16x8 bn = pack8(enc_hid(F, x_nxt), hn);
        f32x4 dh = mfma32(F.hwA, bn, F.biasH);
        soft_store(dh, a, idx, active, hi, out);
        bb = bn;
    }

    if (ch == NC-1) {
        if (active) {                          // no reset in entire chunk
#pragma unroll
            for (int r = 0; r < 4; r++) {
                out[OFF_HN + b*16 + 4*hi + r] = (float)bb[4+r];
                out[OFF_CN + b*16 + 4*hi + r] = cc[r];
            }
        } else if (valid[(NC-1)*BB + b]) {
#pragma unroll
            for (int r = 0; r < 4; r++) {
                out[OFF_HN + b*16 + 4*hi + r] = carry[((NC-1)*32 + 4*hi + r)*BB + b];
                out[OFF_CN + b*16 + 4*hi + r] = carry[((NC-1)*32 + 16 + 4*hi + r)*BB + b];
            }
        } // else: phase 3 writes
    }
}

// ---- exact scalar f32 fallback cell (phase 3 only; ~never executes) ------
__device__ void cell_scalar(const float* x, const int* action,
    const float* w1, const float* b1, const float* w_ih, const float* w_hh,
    const float* bsum, const float* actor_w, const float* actor_b,
    const float* critic_w, const float* critic_b, float* out,
    int t, int b, float h[16], float c[16])
{
    const int idx = t*BB + b;
    float x0 = x[2*(size_t)idx], x1 = x[2*(size_t)idx+1];
    float hid[16];
#pragma unroll
    for (int k = 0; k < 16; k++)
        hid[k] = fmaxf(fmaf(w1[2*k], x0, fmaf(w1[2*k+1], x1, b1[k])), 0.f);
    float nh[16], nc[16];
#pragma unroll
    for (int k = 0; k < 16; k++) {
        float ai = bsum[k], af = bsum[16+k], ag = bsum[32+k], ao = bsum[48+k];
#pragma unroll
        for (int j = 0; j < 16; j++) {
            ai = fmaf(w_ih[k*16+j],      hid[j], ai);
            af = fmaf(w_ih[(16+k)*16+j], hid[j], af);
            ag = fmaf(w_ih[(32+k)*16+j], hid[j], ag);
            ao = fmaf(w_ih[(48+k)*16+j], hid[j], ao);
        }
#pragma unroll
        for (int j = 0; j < 16; j++) {
            ai = fmaf(w_hh[k*16+j],      h[j], ai);
            af = fmaf(w_hh[(16+k)*16+j], h[j], af);
            ag = fmaf(w_hh[(32+k)*16+j], h[j], ag);
            ao = fmaf(w_hh[(48+k)*16+j], h[j], ao);
        }
        float si = fsig(ai), sf = fsig(af), sg = ftanh_(ag), so = fsig(ao);
        float cv = fmaf(sf, c[k], si*sg);
        nc[k] = cv; nh[k] = so*ftanh_(cv);
    }
#pragma unroll
    for (int k = 0; k < 16; k++) { h[k] = nh[k]; c[k] = nc[k]; }
    float l0=actor_b[0], l1=actor_b[1], l2=actor_b[2], l3=actor_b[3], v=critic_b[0];
#pragma unroll
    for (int j = 0; j < 16; j++) {
        l0 = fmaf(actor_w[j],    h[j], l0);
        l1 = fmaf(actor_w[16+j], h[j], l1);
        l2 = fmaf(actor_w[32+j], h[j], l2);
        l3 = fmaf(actor_w[48+j], h[j], l3);
        v  = fmaf(critic_w[j],   h[j], v);
    }
    float mx = fmaxf(fmaxf(l0,l1), fmaxf(l2,l3));
    float e0=__expf(l0-mx), e1=__expf(l1-mx), e2=__expf(l2-mx), e3=__expf(l3-mx);
    float s = e0+e1+e2+e3, ls = __logf(s), inv = __builtin_amdgcn_rcpf(s);
    float lp0=l0-mx-ls, lp1=l1-mx-ls, lp2=l2-mx-ls, lp3=l3-mx-ls;
    int a = action[idx];
    float lp = (a==0)?lp0:(a==1)?lp1:(a==2)?lp2:lp3;
    out[idx]            = (float)a;
    out[OFF_LOGP + idx] = lp;
    out[OFF_ENT  + idx] = -(e0*lp0+e1*lp1+e2*lp2+e3*lp3)*inv;
    out[OFF_VAL  + idx] = v;
}

// Phase 3: sequential per-env fixup for chunks with no reset (P ~ 2^-32 each).
__global__ void k_phase3(KPARAMS)
{
    int b = blockIdx.x*blockDim.x + threadIdx.x;
    if (b >= BB) return;
    bool anybad = false;
    for (int ch = 0; ch < NC; ch++) anybad |= (valid[ch*BB + b] == 0);
    if (!anybad) return;

    int fixed_until = 0;
    for (int ch = 0; ch < NC; ch++) {
        if (valid[ch*BB + b]) continue;
        int t0 = ch << LCH;
        if (t0 < fixed_until) continue;
        float h[16], c[16];
        if (ch == 0) {
#pragma unroll
            for (int k = 0; k < 16; k++) { h[k] = h0[b*16+k]; c[k] = c0[b*16+k]; }
        } else {
#pragma unroll
            for (int k = 0; k < 16; k++) {
                h[k] = carry[((ch-1)*32 + k)*BB + b];
                c[k] = carry[((ch-1)*32 + 16 + k)*BB + b];
            }
        }
        int t;
        for (t = t0; t < TT; t++) {
            if (done[t*BB + b]) break;
            cell_scalar(x, action, w1, b1, w_ih, w_hh, bsum,
                        actor_w, actor_b, critic_w, critic_b, out, t, b, h, c);
            if (((t+1) & (CH-1)) == 0) {
                int cc2 = t >> LCH;
#pragma unroll
                for (int k = 0; k < 16; k++) {
                    carry[(cc2*32 + k)*BB + b]      = h[k];
                    carry[(cc2*32 + 16 + k)*BB + b] = c[k];
                }
                valid[cc2*BB + b] = 1;
            }
        }
        if (t == TT) {
#pragma unroll
            for (int k = 0; k < 16; k++) {
                out[OFF_HN + b*16 + k] = h[k];
                out[OFF_CN + b*16 + k] = c[k];
            }
        }
        fixed_until = t;
    }
    if (valid[(NC-1)*BB + b]) {
#pragma unroll
        for (int k = 0; k < 16; k++) {
            out[OFF_HN + b*16 + k] = carry[((NC-1)*32 + k)*BB + b];
            out[OFF_CN + b*16 + k] = carry[((NC-1)*32 + 16 + k)*BB + b];
        }
    }
}

// Prep: bsum exact (phase3); bsum_s/wih_s/whh_s pre-scaled for exp2 gates
// (i,f,o rows: -log2e; g rows 32..47: -2log2e); hw16 head matrix.
__global__ void k_prep(const float* __restrict__ b_ih, const float* __restrict__ b_hh,
                       const float* __restrict__ w_ih, const float* __restrict__ w_hh,
                       const float* __restrict__ actor_w, const float* __restrict__ critic_w,
                       float* __restrict__ bsum, float* __restrict__ bsum_s,
                       float* __restrict__ hw16, float* __restrict__ wih_s,
                       float* __restrict__ whh_s)
{
    int i = threadIdx.x;
    if (i < 64) {
        float s = b_ih[i] + b_hh[i];
        bsum[i] = s;
        bool isg = (i >= 32) && (i < 48);
        bsum_s[i] = s * (isg ? N2L2E : NL2E);
    }
    {
        int row = i >> 4, k = i & 15;
        float v = 0.f;
        if (row < 4)        v = actor_w[row*16 + k];
        else if (row == 4)  v = critic_w[k];
        hw16[i] = v;
    }
    for (int j = i; j < 1024; j += 256) {
        int row = j >> 4;
        float sc = ((row >= 32) && (row < 48)) ? N2L2E : NL2E;
        wih_s[j] = sc * w_ih[j];
        whh_s[j] = sc * w_hh[j];
    }
}

extern "C" void kernel_launch(void* const* d_in, const int* in_sizes, int n_in,
                              void* d_out, int out_size, void* d_ws, size_t ws_size,
                              hipStream_t stream)
{
    const float* x        = (const float*)d_in[0];
    const int*   done     = (const int*)  d_in[1];
    const int*   action   = (const int*)  d_in[2];
    const float* h0       = (const float*)d_in[3];
    const float* c0       = (const float*)d_in[4];
    const float* w1       = (const float*)d_in[5];
    const float* b1       = (const float*)d_in[6];
    const float* w_ih     = (const float*)d_in[7];
    const float* w_hh     = (const float*)d_in[8];
    const float* b_ih     = (const float*)d_in[9];
    const float* b_hh     = (const float*)d_in[10];
    const float* actor_w  = (const float*)d_in[11];
    const float* actor_b  = (const float*)d_in[12];
    const float* critic_w = (const float*)d_in[13];
    const float* critic_b = (const float*)d_in[14];
    float* out = (float*)d_out;

    // ws: bsum@0 | bsum_s@256 | hw16@512 | wih_s@1536 | whh_s@5632 | carry@16384 | valid
    float* bsum   = (float*)d_ws;
    float* bsum_s = (float*)((char*)d_ws + 256);
    float* hw16   = (float*)((char*)d_ws + 512);
    float* wih_s  = (float*)((char*)d_ws + 1536);
    float* whh_s  = (float*)((char*)d_ws + 5632);
    float* carry  = (float*)((char*)d_ws + 16384);
    int*   valid  = (int*)((char*)d_ws + 16384 + (size_t)NC*32*BB*4);

    hipLaunchKernelGGL(k_prep, dim3(1), dim3(256), 0, stream,
                       b_ih, b_hh, w_ih, w_hh, actor_w, critic_w,
                       bsum, bsum_s, hw16, wih_s, whh_s);

    const int nthreads = NC*(BB/16)*64;            // one wave per 16 envs
    hipLaunchKernelGGL(k_phase1, dim3(nthreads/64), dim3(64), 0, stream, KARGS);
    hipLaunchKernelGGL(k_phase2, dim3(nthreads/64), dim3(64), 0, stream, KARGS);
    hipLaunchKernelGGL(k_phase3, dim3(BB/256), dim3(256), 0, stream, KARGS);
}